// Round 4
// baseline (82.691 us; speedup 1.0000x reference)
//
#include <hip/hip_runtime.h>

#define NQ 10

typedef float v2f __attribute__((ext_vector_type(2)));

__device__ __forceinline__ int   f2i(float v) { union { float f; int i; } u; u.f = v; return u.i; }
__device__ __forceinline__ float i2f(int v)   { union { int i; float f; } u; u.i = v; return u.f; }

__device__ __forceinline__ v2f cmul(v2f a, v2f b) {
    return (v2f){ fmaf(a.x, b.x, -a.y * b.y), fmaf(a.x, b.y, a.y * b.x) };
}

// ---- VOP3P packed complex helpers (verified R3). K = (coef_tp0, coef_tp1);
// compile-time SP picks the half via op_sel. i-variant adds K.sel*(i*a). ----
template<int SP> __device__ __forceinline__ v2f pk_mul_sel(v2f a, v2f K) {
    v2f d;
    if constexpr (SP == 0)
        asm("v_pk_mul_f32 %0, %1, %2 op_sel:[0,0] op_sel_hi:[1,0]" : "=v"(d) : "v"(a), "v"(K));
    else
        asm("v_pk_mul_f32 %0, %1, %2 op_sel:[0,1] op_sel_hi:[1,1]" : "=v"(d) : "v"(a), "v"(K));
    return d;
}
template<int SP> __device__ __forceinline__ v2f pk_fma_sel(v2f a, v2f K, v2f c) {
    v2f d;
    if constexpr (SP == 0)
        asm("v_pk_fma_f32 %0, %1, %2, %3 op_sel:[0,0,0] op_sel_hi:[1,0,1]"
            : "=v"(d) : "v"(a), "v"(K), "v"(c));
    else
        asm("v_pk_fma_f32 %0, %1, %2, %3 op_sel:[0,1,0] op_sel_hi:[1,1,1]"
            : "=v"(d) : "v"(a), "v"(K), "v"(c));
    return d;
}
template<int SP> __device__ __forceinline__ v2f pk_fma_i_sel(v2f a, v2f K, v2f c) {
    v2f d;
    if constexpr (SP == 0)
        asm("v_pk_fma_f32 %0, %1, %2, %3 op_sel:[1,0,0] op_sel_hi:[0,0,1] neg_lo:[1,0,0]"
            : "=v"(d) : "v"(a), "v"(K), "v"(c));
    else
        asm("v_pk_fma_f32 %0, %1, %2, %3 op_sel:[1,1,0] op_sel_hi:[0,1,1] neg_lo:[1,0,0]"
            : "=v"(d) : "v"(a), "v"(K), "v"(c));
    return d;
}

// ---- lane exchange: identity / DPP / ds_swizzle / ds_bpermute by LM ----
template<int LM>
__device__ __forceinline__ v2f xlane(v2f v, int baddr) {
    if constexpr (LM == 0) return v;
    int x = f2i(v.x), y = f2i(v.y);
    if constexpr (LM == 1) {
        x = __builtin_amdgcn_mov_dpp(x, 177, 0xF, 0xF, false);
        y = __builtin_amdgcn_mov_dpp(y, 177, 0xF, 0xF, false);
    } else if constexpr (LM == 2) {
        x = __builtin_amdgcn_mov_dpp(x, 78, 0xF, 0xF, false);
        y = __builtin_amdgcn_mov_dpp(y, 78, 0xF, 0xF, false);
    } else if constexpr (LM == 3) {
        x = __builtin_amdgcn_mov_dpp(x, 27, 0xF, 0xF, false);
        y = __builtin_amdgcn_mov_dpp(y, 27, 0xF, 0xF, false);
    } else if constexpr (LM < 32) {
        constexpr int off = (LM << 10) | 0x1F;   // BitMode xor
        x = __builtin_amdgcn_ds_swizzle(x, off);
        y = __builtin_amdgcn_ds_swizzle(y, off);
    } else {
        x = __builtin_amdgcn_ds_bpermute(baddr, x);
        y = __builtin_amdgcn_ds_bpermute(baddr, y);
    }
    return (v2f){ i2f(x), i2f(y) };
}

struct Kset { v2f Ar, Ai, Br, Bi; };

// fuse Rot * RY(c,s), pack coefficient pairs per total-parity with lp swap
__device__ __forceinline__ Kset build_K(float4 r0, float4 r1, float cq, float sq, int lp)
{
    const float g00r = fmaf(r0.x, cq,  r0.z * sq), g00i = fmaf(r0.y, cq,  r0.w * sq);
    const float g01r = fmaf(r0.z, cq, -r0.x * sq), g01i = fmaf(r0.w, cq, -r0.y * sq);
    const float g10r = fmaf(r1.x, cq,  r1.z * sq), g10i = fmaf(r1.y, cq,  r1.w * sq);
    const float g11r = fmaf(r1.z, cq, -r1.x * sq), g11i = fmaf(r1.w, cq, -r1.y * sq);
    Kset K;
    K.Ar = lp ? (v2f){g11r, g00r} : (v2f){g00r, g11r};
    K.Ai = lp ? (v2f){g11i, g00i} : (v2f){g00i, g11i};
    K.Br = lp ? (v2f){g10r, g01r} : (v2f){g01r, g10r};
    K.Bi = lp ? (v2f){g10i, g01i} : (v2f){g01i, g10i};
    return K;
}

#define QNN_FMA8                                                              \
    QNN_F(0) QNN_F(1) QNN_F(2) QNN_F(3) QNN_F(4) QNN_F(5) QNN_F(6) QNN_F(7)
#define QNN_F(J) { constexpr int SP_ = __builtin_popcount((J) & RJ) & 1;      \
    v2f t_ = pk_mul_sel<SP_>(a[J], K.Ar);                                     \
    t_ = pk_fma_i_sel<SP_>(a[J], K.Ai, t_);                                   \
    t_ = pk_fma_sel<SP_>(o[J], K.Br, t_);                                     \
    t_ = pk_fma_i_sel<SP_>(o[J], K.Bi, t_);                                   \
    a[J] = t_; }

// regular gate (mask bit 9 clear): in-wave exchange, prefetch all partners
template<int M, int RJ, int RL, int RW>
__device__ __forceinline__ void gate_reg(v2f (&a)[8], float4 r0, float4 r1,
                                         float cq, float sq, int lane, int wv)
{
    constexpr int JM = M & 7;
    constexpr int LM = (M >> 3) & 63;
    int lp = 0;
    if constexpr (RL != 0) lp = __popc(lane & RL) & 1;
    if constexpr (RW != 0) lp ^= wv;
    const Kset K = build_K(r0, r1, cq, sq, lp);
    const int baddr = (lane ^ LM) << 2;
    v2f o[8];
    #pragma unroll
    for (int j = 0; j < 8; ++j) o[j] = xlane<LM>(a[j ^ JM], baddr);
    QNN_FMA8
}

// wave-crossing gate (mask bit 9 set): LDS stage, slot-major (conflict-light)
template<int M, int RJ, int RL, int RW>
__device__ __forceinline__ void gate_wm(v2f (&a)[8], v2f* stage, float4 r0, float4 r1,
                                        float cq, float sq, int tid, int wv)
{
    constexpr int JM = M & 7;
    constexpr int LW = (M >> 3) & 127;   // lane+wave xor on tid
    const int lane = tid & 63;
    int lp = 0;
    if constexpr (RL != 0) lp = __popc(lane & RL) & 1;
    if constexpr (RW != 0) lp ^= wv;
    const Kset K = build_K(r0, r1, cq, sq, lp);
    #pragma unroll
    for (int j = 0; j < 8; ++j) stage[j * 128 + tid] = a[j];
    __syncthreads();
    const int pt = tid ^ LW;
    v2f o[8];
    #pragma unroll
    for (int j = 0; j < 8; ++j) o[j] = stage[(j ^ JM) * 128 + pt];
    __syncthreads();
    QNN_FMA8
}

__global__ __launch_bounds__(128, 8)
void qnn_kernel(const float* __restrict__ x, const float* __restrict__ w,
                float* __restrict__ out)
{
    __shared__ float4 rotL[3 * NQ][2];   // (R00,R01) | (R10,R11)
    __shared__ v2f    stage[1024];       // 8 KB full-state staging
    __shared__ float  zred[2][NQ];

    const int t    = threadIdx.x;
    const int lane = t & 63;
    const int wv   = t >> 6;             // physical bit 9
    const int b    = blockIdx.x;         // one batch element per block

    if (t < 3 * NQ) {
        const float* wp = w + t * 3;
        float phi = wp[0], th = wp[1], om = wp[2];
        float ct = cosf(th * 0.5f), st = sinf(th * 0.5f);
        float ap = (phi + om) * 0.5f, am = (phi - om) * 0.5f;
        float cap = cosf(ap), sap = sinf(ap);
        float cam = cosf(am), sam = sinf(am);
        rotL[t][0] = make_float4(cap * ct, -sap * ct, -cam * st, -sam * st);
        rotL[t][1] = make_float4(cam * st, -sam * st,  cap * ct,  sap * ct);
    }
    __syncthreads();

    // per-batch RY cos/sin, wave-uniform -> nudge into SGPRs
    const float* xb = x + (size_t)(b * NQ);
    float c_[NQ], s_[NQ];
    #pragma unroll
    for (int q = 0; q < NQ; ++q) {
        float xv = xb[q] * 0.5f;
        c_[q] = i2f(__builtin_amdgcn_readfirstlane(f2i(__cosf(xv))));
        s_[q] = i2f(__builtin_amdgcn_readfirstlane(f2i(__sinf(xv))));
    }

    // ---- layer 1 analytic product state: bits 0-2 slot, 3-8 lane, 9 wave ----
    v2f tq[3][2], Ln, Wf;
    #pragma unroll
    for (int q = 0; q < NQ; ++q) {
        const float4 r0 = rotL[q][0], r1 = rotL[q][1];
        const float cq = c_[q], sq = s_[q];
        v2f g0 = { fmaf(r0.x, cq, r0.z * sq), fmaf(r0.y, cq, r0.w * sq) };
        v2f g1 = { fmaf(r1.x, cq, r1.z * sq), fmaf(r1.y, cq, r1.w * sq) };
        if (q < 3)      { tq[q][0] = g0; tq[q][1] = g1; }
        else if (q < 9) { v2f gg = ((lane >> (q - 3)) & 1) ? g1 : g0;
                          Ln = (q == 3) ? gg : cmul(Ln, gg); }
        else            { Wf = wv ? g1 : g0; }
    }
    const v2f LWp = cmul(Ln, Wf);
    v2f S01[4];
    #pragma unroll
    for (int j = 0; j < 4; ++j)
        S01[j] = cmul(tq[0][j & 1], tq[1][(j >> 1) & 1]);
    const v2f SH[2] = { cmul(tq[2][0], LWp), cmul(tq[2][1], LWp) };
    v2f a[8];
    #pragma unroll
    for (int j = 0; j < 8; ++j)
        a[j] = cmul(S01[j & 3], SH[j >> 2]);

    // ---- layers 2..3: masks re-split for slot3/lane6/wave1 layout ----
#define GR(IDX, Q, M, RJ, RL, RW) \
    gate_reg<M, RJ, RL, RW>(a, rotL[IDX][0], rotL[IDX][1], c_[Q], s_[Q], lane, wv);
#define GW(IDX, Q, M, RJ, RL, RW) \
    gate_wm<M, RJ, RL, RW>(a, stage, rotL[IDX][0], rotL[IDX][1], c_[Q], s_[Q], t, wv);
    GR(10, 0, 0x003, 6, 63, 1)
    GR(11, 1, 0x006, 3,  0, 0)
    GR(12, 2, 0x00C, 7,  0, 0)
    GR(13, 3, 0x018, 7,  1, 0)
    GR(14, 4, 0x030, 7,  3, 0)
    GR(15, 5, 0x060, 7,  7, 0)
    GR(16, 6, 0x0C0, 7, 15, 0)
    GR(17, 7, 0x180, 7, 31, 0)
    GW(18, 8, 0x300, 7, 63, 0)
    GW(19, 9, 0x203, 7, 63, 1)
    GR(20, 0, 0x005, 3, 21, 1)
    GR(21, 1, 0x00A, 5, 63, 1)
    GR(22, 2, 0x014, 2, 63, 1)
    GR(23, 3, 0x028, 5, 62, 1)
    GR(24, 4, 0x050, 2, 61, 1)
    GR(25, 5, 0x0A0, 5, 58, 1)
    GR(26, 6, 0x140, 2, 53, 1)
    GW(27, 7, 0x280, 5, 42, 1)
    GR(28, 8, 0x103, 2, 21, 1)
    GW(29, 9, 0x206, 5, 42, 0)
#undef GR
#undef GW

    // ---- probabilities + 3-bit Walsh-Hadamard over slots ----
    float P[8];
    #pragma unroll
    for (int j = 0; j < 8; ++j)
        P[j] = fmaf(a[j].x, a[j].x, a[j].y * a[j].y);
    #pragma unroll
    for (int bit = 0; bit < 3; ++bit) {
        #pragma unroll
        for (int j = 0; j < 8; ++j)
            if (!(j & (1 << bit))) {
                int k = j | (1 << bit);
                float u = P[j], v = P[k];
                P[j] = u + v;
                P[k] = u - v;
            }
    }

    const int bp32 = ((lane ^ 32) << 2);
    float vout = 0.f;
#define MEAS(Q, RJ_, RL_, RW_)                                                \
    { float v = P[RJ_];                                                       \
      int ng = __popc(lane & (RL_)) & 1;                                      \
      if (RW_) ng ^= wv;                                                      \
      if (ng) v = -v;                                                         \
      v += i2f(__builtin_amdgcn_mov_dpp(f2i(v), 177, 0xF, 0xF, false));       \
      v += i2f(__builtin_amdgcn_mov_dpp(f2i(v), 78, 0xF, 0xF, false));        \
      v += i2f(__builtin_amdgcn_ds_swizzle(f2i(v), (4 << 10) | 0x1F));        \
      v += i2f(__builtin_amdgcn_ds_swizzle(f2i(v), (8 << 10) | 0x1F));        \
      v += i2f(__builtin_amdgcn_ds_swizzle(f2i(v), (16 << 10) | 0x1F));       \
      v += i2f(__builtin_amdgcn_ds_bpermute(bp32, f2i(v)));                   \
      if (lane == (Q)) vout = v; }
    MEAS(0, 5, 25, 0) MEAS(1, 6, 42, 0) MEAS(2, 4, 21, 1) MEAS(3, 1, 43, 0)
    MEAS(4, 3, 22, 1) MEAS(5, 6, 44, 0) MEAS(6, 4, 25, 1) MEAS(7, 1, 51, 0)
    MEAS(8, 3, 38, 1) MEAS(9, 6, 12, 1)
#undef MEAS

    if (lane < NQ) zred[wv][lane] = vout;
    __syncthreads();
    if (t < NQ) out[b * NQ + t] = zred[0][t] + zred[1][t];
}

extern "C" void kernel_launch(void* const* d_in, const int* in_sizes, int n_in,
                              void* d_out, int out_size, void* d_ws, size_t ws_size,
                              hipStream_t stream) {
    const float* x = (const float*)d_in[0];   // (4096, 10) f32
    const float* w = (const float*)d_in[1];   // (3, 10, 3) f32
    float* out = (float*)d_out;               // (4096, 10) f32
    const int B = in_sizes[0] / NQ;           // 4096
    qnn_kernel<<<B, 128, 0, stream>>>(x, w, out);
}

// Round 5
// 78.419 us; speedup vs baseline: 1.0545x; 1.0545x over previous
//
#include <hip/hip_runtime.h>

#define NQ 10
#define NL 3

typedef float v2f __attribute__((ext_vector_type(2)));

__device__ __forceinline__ int   f2i(float v) { union { float f; int i; } u; u.f = v; return u.i; }
__device__ __forceinline__ float i2f(int v)   { union { int i; float f; } u; u.i = v; return u.f; }

__device__ __forceinline__ v2f cmul(v2f a, v2f b) {
    return (v2f){ fmaf(a.x, b.x, -a.y * b.y), fmaf(a.x, b.y, a.y * b.x) };
}

template<int C> __device__ __forceinline__ int dppm(int v) {
    return __builtin_amdgcn_mov_dpp(v, C, 0xF, 0xF, false);
}

// ---- VOP3P packed complex helpers (verified R3/R4). K = (coef_tp0, coef_tp1);
// compile-time SP picks the half via op_sel. i-variant adds K.sel*(i*a). ----
template<int SP> __device__ __forceinline__ v2f pk_mul_sel(v2f a, v2f K) {
    v2f d;
    if constexpr (SP == 0)
        asm("v_pk_mul_f32 %0, %1, %2 op_sel:[0,0] op_sel_hi:[1,0]" : "=v"(d) : "v"(a), "v"(K));
    else
        asm("v_pk_mul_f32 %0, %1, %2 op_sel:[0,1] op_sel_hi:[1,1]" : "=v"(d) : "v"(a), "v"(K));
    return d;
}
template<int SP> __device__ __forceinline__ v2f pk_fma_sel(v2f a, v2f K, v2f c) {
    v2f d;
    if constexpr (SP == 0)
        asm("v_pk_fma_f32 %0, %1, %2, %3 op_sel:[0,0,0] op_sel_hi:[1,0,1]"
            : "=v"(d) : "v"(a), "v"(K), "v"(c));
    else
        asm("v_pk_fma_f32 %0, %1, %2, %3 op_sel:[0,1,0] op_sel_hi:[1,1,1]"
            : "=v"(d) : "v"(a), "v"(K), "v"(c));
    return d;
}
template<int SP> __device__ __forceinline__ v2f pk_fma_i_sel(v2f a, v2f K, v2f c) {
    v2f d;
    if constexpr (SP == 0)
        asm("v_pk_fma_f32 %0, %1, %2, %3 op_sel:[1,0,0] op_sel_hi:[0,0,1] neg_lo:[1,0,0]"
            : "=v"(d) : "v"(a), "v"(K), "v"(c));
    else
        asm("v_pk_fma_f32 %0, %1, %2, %3 op_sel:[1,1,0] op_sel_hi:[0,1,1] neg_lo:[1,0,0]"
            : "=v"(d) : "v"(a), "v"(K), "v"(c));
    return d;
}

// ---- lane exchange by xor mask LM. Single-DPP: 1,2,3 (quad_perm), 7
// (row_half_mirror=0x141), 15 (row_mirror=0x140). Double-DPP compositions:
// 4=7^3, 5=7^2, 6=7^1, 8=15^7, 12=15^3 (xor masks compose). Else ds_swizzle
// (<32) / ds_bpermute (>=32). ----
template<int LM>
__device__ __forceinline__ v2f xlane(v2f v, int baddr) {
    if constexpr (LM == 0) return v;
    int x = f2i(v.x), y = f2i(v.y);
    if constexpr (LM == 1)       { x = dppm<177>(x);            y = dppm<177>(y); }
    else if constexpr (LM == 2)  { x = dppm<78>(x);             y = dppm<78>(y); }
    else if constexpr (LM == 3)  { x = dppm<27>(x);             y = dppm<27>(y); }
    else if constexpr (LM == 7)  { x = dppm<321>(x);            y = dppm<321>(y); }
    else if constexpr (LM == 15) { x = dppm<320>(x);            y = dppm<320>(y); }
    else if constexpr (LM == 4)  { x = dppm<321>(dppm<27>(x));  y = dppm<321>(dppm<27>(y)); }
    else if constexpr (LM == 5)  { x = dppm<321>(dppm<78>(x));  y = dppm<321>(dppm<78>(y)); }
    else if constexpr (LM == 6)  { x = dppm<321>(dppm<177>(x)); y = dppm<321>(dppm<177>(y)); }
    else if constexpr (LM == 8)  { x = dppm<320>(dppm<321>(x)); y = dppm<320>(dppm<321>(y)); }
    else if constexpr (LM == 12) { x = dppm<320>(dppm<27>(x));  y = dppm<320>(dppm<27>(y)); }
    else if constexpr (LM < 32) {
        constexpr int off = (LM << 10) | 0x1F;   // BitMode xor
        x = __builtin_amdgcn_ds_swizzle(x, off);
        y = __builtin_amdgcn_ds_swizzle(y, off);
    } else {
        x = __builtin_amdgcn_ds_bpermute(baddr, x);
        y = __builtin_amdgcn_ds_bpermute(baddr, y);
    }
    return (v2f){ i2f(x), i2f(y) };
}

// Generalized single-qubit gate under GF(2) index transform (masks verified R2/R3).
// Restructured vs R3: prefetch ALL partner values first (batched DS issue),
// then the packed-FMA sweep — hides exchange latency within the gate.
template<int MASK, int RMASK>
__device__ __forceinline__ void apply_gate(v2f (&a)[16], float4 r0, float4 r1,
                                           float cq, float sq, int lane)
{
    constexpr int LM = (MASK >> 4) & 63;
    constexpr int JM = MASK & 15;
    constexpr int RH = (RMASK >> 4) & 63;
    constexpr int RL = RMASK & 15;

    // fuse Rot * RY(c,s)
    const float g00r = fmaf(r0.x, cq,  r0.z * sq), g00i = fmaf(r0.y, cq,  r0.w * sq);
    const float g01r = fmaf(r0.z, cq, -r0.x * sq), g01i = fmaf(r0.w, cq, -r0.y * sq);
    const float g10r = fmaf(r1.x, cq,  r1.z * sq), g10i = fmaf(r1.y, cq,  r1.w * sq);
    const float g11r = fmaf(r1.z, cq, -r1.x * sq), g11i = fmaf(r1.w, cq, -r1.y * sq);

    const int lp = (RH != 0) ? (__popc(lane & RH) & 1) : 0;
    const v2f KAr = lp ? (v2f){g11r, g00r} : (v2f){g00r, g11r};
    const v2f KAi = lp ? (v2f){g11i, g00i} : (v2f){g00i, g11i};
    const v2f KBr = lp ? (v2f){g10r, g01r} : (v2f){g01r, g10r};
    const v2f KBi = lp ? (v2f){g10i, g01i} : (v2f){g01i, g10i};

    const int baddr = ((lane ^ LM) << 2);

    // phase 1: all partner values (independent -> DS ops pipeline back-to-back)
    v2f o[16];
    #pragma unroll
    for (int j = 0; j < 16; ++j) o[j] = xlane<LM>(a[j ^ JM], baddr);

    // phase 2: packed complex FMAs, slot parity folded into op_sel at compile time
#define QNN_F(J) { constexpr int SP_ = __builtin_popcount((J) & RL) & 1;      \
    v2f t_ = pk_mul_sel<SP_>(a[J], KAr);                                      \
    t_ = pk_fma_i_sel<SP_>(a[J], KAi, t_);                                    \
    t_ = pk_fma_sel<SP_>(o[J], KBr, t_);                                      \
    t_ = pk_fma_i_sel<SP_>(o[J], KBi, t_);                                    \
    a[J] = t_; }
    QNN_F(0) QNN_F(1) QNN_F(2) QNN_F(3) QNN_F(4) QNN_F(5) QNN_F(6) QNN_F(7)
    QNN_F(8) QNN_F(9) QNN_F(10) QNN_F(11) QNN_F(12) QNN_F(13) QNN_F(14) QNN_F(15)
#undef QNN_F
}

__global__ __launch_bounds__(256, 4)
void qnn_kernel(const float* __restrict__ x, const float* __restrict__ w,
                float* __restrict__ out)
{
    __shared__ float4 rotL[NL * NQ][2];   // (R00,R01) | (R10,R11)

    const int t    = threadIdx.x;
    const int lane = t & 63;
    const int b    = blockIdx.x * 4 + (t >> 6);   // one wave per batch element

    if (t < NL * NQ) {
        const float* wp = w + t * 3;
        float phi = wp[0], th = wp[1], om = wp[2];
        float ct = cosf(th * 0.5f), st = sinf(th * 0.5f);
        float ap = (phi + om) * 0.5f, am = (phi - om) * 0.5f;
        float cap = cosf(ap), sap = sinf(ap);
        float cam = cosf(am), sam = sinf(am);
        rotL[t][0] = make_float4(cap * ct, -sap * ct, -cam * st, -sam * st);
        rotL[t][1] = make_float4(cam * st, -sam * st,  cap * ct,  sap * ct);
    }
    __syncthreads();

    // ---- per-batch RY cos/sin (wave-uniform -> SGPR via readfirstlane) ----
    const float* xb = x + (size_t)__builtin_amdgcn_readfirstlane(b * NQ);
    float c_[NQ], s_[NQ];
    #pragma unroll
    for (int q = 0; q < NQ; ++q) {
        float xv = xb[q] * 0.5f;
        c_[q] = i2f(__builtin_amdgcn_readfirstlane(f2i(__cosf(xv))));
        s_[q] = i2f(__builtin_amdgcn_readfirstlane(f2i(__sinf(xv))));
    }

    // ---- layer 1 analytic: product state amp[p] = prod_q col0(G_q)[bit_q(p)] ----
    v2f c0[4], c1[4];          // slot qubits 0..3 (col-0 coefficients)
    v2f Ln = {1.f, 0.f};       // lane-bit product (qubits 4..9)
    #pragma unroll
    for (int q = 0; q < NQ; ++q) {
        float4 r0 = rotL[q][0], r1 = rotL[q][1];
        float cq = c_[q], sq = s_[q];
        v2f g0 = { fmaf(r0.x, cq, r0.z * sq), fmaf(r0.y, cq, r0.w * sq) };
        v2f g1 = { fmaf(r1.x, cq, r1.z * sq), fmaf(r1.y, cq, r1.w * sq) };
        if (q < 4) { c0[q] = g0; c1[q] = g1; }
        else {
            v2f gg = ((lane >> (q - 4)) & 1) ? g1 : g0;
            Ln = (q == 4) ? gg : cmul(Ln, gg);
        }
    }
    v2f S01[4], SH[4];
    #pragma unroll
    for (int j = 0; j < 4; ++j)
        S01[j] = cmul((j & 1) ? c1[0] : c0[0], (j & 2) ? c1[1] : c0[1]);
    #pragma unroll
    for (int h = 0; h < 4; ++h)
        SH[h] = cmul(cmul((h & 1) ? c1[2] : c0[2], (h & 2) ? c1[3] : c0[3]), Ln);
    v2f a[16];
    #pragma unroll
    for (int j = 0; j < 16; ++j)
        a[j] = cmul(S01[j & 3], SH[j >> 2]);

    // ---- layers 2..3 (masks + parities verified in R2/R3) ----
#define GATE(IDX, Q, MASK, RMASK) \
    apply_gate<MASK, RMASK>(a, rotL[IDX][0], rotL[IDX][1], c_[Q], s_[Q], lane);
    GATE(10, 0, 0x003, 0x3FE)  GATE(11, 1, 0x006, 0x003)
    GATE(12, 2, 0x00C, 0x007)  GATE(13, 3, 0x018, 0x00F)
    GATE(14, 4, 0x030, 0x01F)  GATE(15, 5, 0x060, 0x03F)
    GATE(16, 6, 0x0C0, 0x07F)  GATE(17, 7, 0x180, 0x0FF)
    GATE(18, 8, 0x300, 0x1FF)  GATE(19, 9, 0x203, 0x3FF)
    GATE(20, 0, 0x005, 0x2AB)  GATE(21, 1, 0x00A, 0x3FD)
    GATE(22, 2, 0x014, 0x3FA)  GATE(23, 3, 0x028, 0x3F5)
    GATE(24, 4, 0x050, 0x3EA)  GATE(25, 5, 0x0A0, 0x3D5)
    GATE(26, 6, 0x140, 0x3AA)  GATE(27, 7, 0x280, 0x355)
    GATE(28, 8, 0x103, 0x2AA)  GATE(29, 9, 0x206, 0x155)
#undef GATE

    // ---- probabilities + 4-bit Walsh-Hadamard over slots ----
    float P[16];
    #pragma unroll
    for (int j = 0; j < 16; ++j)
        P[j] = fmaf(a[j].x, a[j].x, a[j].y * a[j].y);
    #pragma unroll
    for (int bit = 0; bit < 4; ++bit) {
        #pragma unroll
        for (int j = 0; j < 16; ++j)
            if (!(j & (1 << bit))) {
                int k = j | (1 << bit);
                float u = P[j], v = P[k];
                P[j] = u + v;
                P[k] = u - v;
            }
    }

    const int bp32 = ((lane ^ 32) << 2);
    float vout = 0.f;
#define MEAS(Q, RM)                                                           \
    { constexpr int RH_ = ((RM) >> 4) & 63;                                   \
      constexpr int RL_ = (RM) & 15;                                          \
      float v = P[RL_];                                                       \
      if (__popc(lane & RH_) & 1) v = -v;                                     \
      v += i2f(dppm<177>(f2i(v)));                 /* xor1  */                \
      v += i2f(dppm<78>(f2i(v)));                  /* xor2  */                \
      v += i2f(dppm<321>(dppm<27>(f2i(v))));       /* xor4 = 7^3 */           \
      v += i2f(dppm<320>(dppm<321>(f2i(v))));      /* xor8 = 15^7 */          \
      v += i2f(__builtin_amdgcn_ds_swizzle(f2i(v), (16 << 10) | 0x1F));       \
      v += i2f(__builtin_amdgcn_ds_bpermute(bp32, f2i(v)));                   \
      if (lane == (Q)) vout = v; }
    MEAS(0, 0x0CD) MEAS(1, 0x156) MEAS(2, 0x2AC) MEAS(3, 0x159)
    MEAS(4, 0x2B3) MEAS(5, 0x166) MEAS(6, 0x2CC) MEAS(7, 0x199)
    MEAS(8, 0x333) MEAS(9, 0x266)
#undef MEAS

    if (lane < NQ) out[b * NQ + lane] = vout;
}

extern "C" void kernel_launch(void* const* d_in, const int* in_sizes, int n_in,
                              void* d_out, int out_size, void* d_ws, size_t ws_size,
                              hipStream_t stream) {
    const float* x = (const float*)d_in[0];   // (4096, 10) f32
    const float* w = (const float*)d_in[1];   // (3, 10, 3) f32
    float* out = (float*)d_out;               // (4096, 10) f32
    const int B = in_sizes[0] / NQ;           // 4096
    qnn_kernel<<<B / 4, 256, 0, stream>>>(x, w, out);
}